// Round 7
// baseline (196.471 us; speedup 1.0000x reference)
//
#include <hip/hip_runtime.h>

#define SQ 2048
#define DH 64
#define NH 12
#define NBH 48          // B*H
#define QTILE 128       // q rows per block (64 per wave, 2 q-groups of 32)
#define KTILE 64        // keys per iteration (32 per wave)
#define NITER (SQ / KTILE)
#define NQT (SQ / QTILE)   // 16 q-tiles -> 768 blocks = 3 blocks/CU

// LDS arena bases (literal)
#define KB0 0
#define KB1 8192
#define VB0 16384
#define VB1 24576

typedef short short8 __attribute__((ext_vector_type(8)));
typedef float f32x2  __attribute__((ext_vector_type(2)));
typedef float f32x4  __attribute__((ext_vector_type(4)));
typedef float f32x16 __attribute__((ext_vector_type(16)));
typedef int   i32x2 __attribute__((ext_vector_type(2)));
typedef int   i32x4 __attribute__((ext_vector_type(4)));

#define MFMA32(a, b, c) __builtin_amdgcn_mfma_f32_32x32x16_bf16(a, b, c, 0, 0, 0)

typedef __attribute__((address_space(1))) const void* gas_ptr;
typedef __attribute__((address_space(3))) void* las_ptr;

__device__ __forceinline__ void load_lds16(const void* g, void* l) {
    // 16B/lane direct global->LDS DMA; LDS dest = wave-uniform base + lane*16
    __builtin_amdgcn_global_load_lds((gas_ptr)g, (las_ptr)l, 16, 0, 0);
}

// two fp32 -> packed bf16x2 (low = a, high = b), RTNE
#if defined(__has_builtin) && __has_builtin(__builtin_amdgcn_cvt_pk_bf16_f32)
typedef __bf16 bf16x2_t __attribute__((ext_vector_type(2)));
__device__ __forceinline__ unsigned pk2bf(float a, float b) {
    bf16x2_t v = __builtin_amdgcn_cvt_pk_bf16_f32(a, b);
    union { bf16x2_t v; unsigned u; } c; c.v = v; return c.u;
}
#else
__device__ __forceinline__ unsigned pk2bf(float a, float b) {
    union { float f; unsigned u; } x, y; x.f = a; y.f = b;
    unsigned ra = x.u + 0x7FFFu + ((x.u >> 16) & 1u);
    unsigned rb = y.u + 0x7FFFu + ((y.u >> 16) & 1u);
    return (ra >> 16) | (rb & 0xFFFF0000u);
}
#endif

#ifdef __has_builtin
#if __has_builtin(__builtin_amdgcn_permlane32_swap)
#define HAVE_PLSWAP 1
#else
#define HAVE_PLSWAP 0
#endif
#else
#define HAVE_PLSWAP 0
#endif

// ------- fused pre-pass: K fp32->bf16 (blocks 0..3071)  |  V transpose (rest) -------
#define KCONV_BLOCKS (NBH * SQ * DH / 8 / 256)   // 3072
__global__ __launch_bounds__(256)
void prepass(const float* __restrict__ K, short* __restrict__ Kb,
             const float* __restrict__ V, short* __restrict__ Vt) {
    __shared__ float Ls[64][68];   // transpose staging (+4 pad)
    if (blockIdx.x < KCONV_BLOCKS) {
        const size_t i = (size_t)(blockIdx.x * 256 + threadIdx.x) * 8;
        f32x4 a = *(const f32x4*)&K[i];
        f32x4 b = *(const f32x4*)&K[i + 4];
        unsigned o[4] = { pk2bf(a[0], a[1]), pk2bf(a[2], a[3]),
                          pk2bf(b[0], b[1]), pk2bf(b[2], b[3]) };
        *(i32x4*)&Kb[i] = *(i32x4*)o;
        return;
    }
    const int bx = blockIdx.x - KCONV_BLOCKS;
    const int st = bx & 31;       // s tile
    const int bh = bx >> 5;
    const int b = bh / NH, h = bh % NH;
    const int s0 = st * 64;
    const float* src = V + ((size_t)b * SQ * NH + (size_t)h) * DH;
    const int dg = threadIdx.x & 15;   // d = 4*dg
    const int sl = threadIdx.x >> 4;   // 0..15
    #pragma unroll
    for (int p = 0; p < 4; ++p) {
        const int row = p * 16 + sl;
        *(f32x4*)&Ls[row][dg * 4] =
            *(const f32x4*)&src[(size_t)(s0 + row) * (NH * DH) + dg * 4];
    }
    __syncthreads();
    const int dr = threadIdx.x >> 2;        // d row 0..63
    const int sc = (threadIdx.x & 3) * 16;  // s chunk
    unsigned out[8];
    #pragma unroll
    for (int jj = 0; jj < 8; ++jj)
        out[jj] = pk2bf(Ls[sc + 2 * jj][dr], Ls[sc + 2 * jj + 1][dr]);
    short* dst = Vt + (size_t)bh * DH * SQ + (size_t)dr * SQ + s0 + sc;
    *(i32x4*)(dst)     = *(i32x4*)&out[0];
    *(i32x4*)(dst + 8) = *(i32x4*)&out[4];
}

// --------- main fused attention (32x32x16 MFMA, 2x-reuse wave decomposition) ---------
// r6 post-mortem: per-CU pipe budget = MFMA 49K cyc (25%), VALU 46K (23%), LDS-READ
// 74K (37%) -> the LDS read port is the BIGGEST pipe; every ds_read fed exactly 1 MFMA
// (wave owned only 32 q rows -> zero A/B-frag reuse). Fix: wave (wq,wk) owns 64 q rows
// (wq) x 32 keys (wk half). Each K-frag read feeds 2 MFMAs (q-groups A,B); each V-frag
// read feeds 2 MFMAs (P-frags A,B). Per wave-tile: 16 MFMAs / 8 ds_reads (was 16/16).
// LDS read pipe halves to ~37K cyc < MFMA pipe. One-time cross-wk combine of (l, O)
// through LDS at the end. Skeleton = r4's best-measured structure (2-buf, syncthreads,
// qk->pv->sm, no setprio).
__global__ __launch_bounds__(256, 3)
void attn_fused_kernel(const float* __restrict__ Q,
                       const short* __restrict__ Kb,   // bf16 [BH][S][D]
                       const short* __restrict__ Vtg,  // bf16 [BH][D][S]
                       float* __restrict__ O) {
    // Kbuf j at KB(j&1) (halves +0 keys0-31, +4096 keys32-63)
    // Vbuf j at VB(j&1) (halves +0 d0-31,    +4096 d32-63)
    // XOR chunk swizzle (chunk c of row r at c^(r&7)); unpadded 128B rows.
    __shared__ __align__(16) char L[32768];

    const int tid  = threadIdx.x;
    const int lane = tid & 63;
    const int w    = tid >> 6;
    const int wq   = w >> 1;        // q-group-of-64 owner (0,1)
    const int wk   = w & 1;         // key-half owner (0,1)
    const int m31  = lane & 31;     // MFMA row/col index
    const int hl   = lane >> 5;     // half-wave 0/1
    const int l7   = lane & 7;

    // ---- XCD-locality swizzle: dispatch round-robins XCDs by (bx & 7).
    const int bx  = blockIdx.x;
    const int xcd = bx & 7;
    const int i96 = bx >> 3;          // 0..95
    const int bh  = xcd * 6 + (i96 % 6);
    const int qt  = i96 / 6;          // 0..15
    const int q0 = qt * QTILE;

    const float* Qb  = Q   + (size_t)bh * SQ * DH;
    const short* Kbh = Kb  + (size_t)bh * SQ * DH;
    const short* Vbh = Vtg + (size_t)bh * DH * SQ;
    float*       Ob  = O   + (size_t)bh * SQ * DH;

    // scale folded into Q, exp as exp2: 1/sqrt(768) * log2(e)
    const float qscale = 0.03608439182435161f * 1.4426950408889634f;

    // ---- Q fragments, 2 q-groups (B operand: n=m31 -> q row, k=16*s+8*hl+j) ----
    short8 qfA[4], qfB[4];
    #pragma unroll
    for (int g = 0; g < 2; ++g) {
        const int qrow = q0 + wq * 64 + g * 32 + m31;
        #pragma unroll
        for (int s = 0; s < 4; ++s) {
            const float* src = Qb + (size_t)qrow * DH + 16 * s + 8 * hl;
            f32x4 qa = *(const f32x4*)src;
            f32x4 qb = *(const f32x4*)(src + 4);
            union { unsigned u[4]; short8 v; } f;
            f.u[0] = pk2bf(qa[0] * qscale, qa[1] * qscale);
            f.u[1] = pk2bf(qa[2] * qscale, qa[3] * qscale);
            f.u[2] = pk2bf(qb[0] * qscale, qb[1] * qscale);
            f.u[3] = pk2bf(qb[2] * qscale, qb[3] * qscale);
            if (g == 0) qfA[s] = f.v; else qfB[s] = f.v;
        }
    }

    // ---- staging source pointers (lane-constant swizzle; block-cooperative) ----
    const int gk = (lane & 7) ^ (lane >> 3);
    const int rr = w * 8 + (lane >> 3);
    const short* kg0 = Kbh + (size_t)rr * DH + gk * 8;
    const short* kg1 = kg0 + 32 * DH;
    const short* vg0 = Vbh + (size_t)rr * SQ + gk * 8;
    const short* vg1 = vg0 + 32 * SQ;
    const int wslot = w * 1024;   // scalar

    // ---- loop-invariant per-lane LDS frag addresses (bytes) ----
    // K read: wave's key half (wk), row = key m31, global chunk (2s+hl) at lds ^(row&7)
    int koff[4];
    #pragma unroll
    for (int s = 0; s < 4; ++s)
        koff[s] = wk * 4096 + m31 * 128 + (((2 * s + hl) ^ l7) * 16);
    // V read: row = d m31 (+4096 imm for d32-63), keys wk*32 + sp*16 + 8hl
    int voff[2];
    #pragma unroll
    for (int sp = 0; sp < 2; ++sp)
        voff[sp] = m31 * 128 + (((4 * wk + 2 * sp + hl) ^ l7) * 16);

    // ---- pipeline state: captured named vars / constant-indexed arrays only ----
    f32x16 oc[4];                // output accumulators [grp*2+dhalf]
    #pragma unroll
    for (int i = 0; i < 4; ++i) oc[i] = (f32x16){};
    f32x16 snA, snB;             // score tiles (q-group A/B x wave's 32 keys)
    short8 pfA[2], pfB[2];       // packed P fragments per q-group (key slices 0,1)
    f32x2 lp[2] = {{0.f, 0.f}, {0.f, 0.f}};   // row-sum accumulators per q-group

    // issue K tile t into Kbuf base kb (2 loads/wave via DMA)
    auto issueK = [&](int kb, int t) {
        const short* p0 = kg0 + (size_t)t * (KTILE * DH);
        const short* p1 = kg1 + (size_t)t * (KTILE * DH);
        load_lds16(p0, L + kb + wslot);
        load_lds16(p1, L + kb + 4096 + wslot);
    };
    // issue V tile t into Vbuf base vb
    auto issueV = [&](int vb, int t) {
        const short* p0 = vg0 + (size_t)t * KTILE;
        const short* p1 = vg1 + (size_t)t * KTILE;
        load_lds16(p0, L + vb + wslot);
        load_lds16(p1, L + vb + 4096 + wslot);
    };

    // QK^T from Kbuf base kb: 4 K-frag reads, each feeding BOTH q-groups (2x reuse)
    auto qk = [&](int kb) {
        f32x16 a = {}, b = {};
        #pragma unroll
        for (int s = 0; s < 4; ++s) {
            short8 ka = *(const short8*)(L + kb + koff[s]);
            a = MFMA32(ka, qfA[s], a);
            b = MFMA32(ka, qfB[s], b);
        }
        snA = a; snB = b;
    };

    // exp + in-register C->A relayout; one score tile -> dst[0..1]; lp[gi] row sums
    auto softmax_pack = [&](const f32x16& sv, short8* dst, int gi) {
        #pragma unroll
        for (int wd = 0; wd < 2; ++wd) {
            float p[8];
            #pragma unroll
            for (int j = 0; j < 8; ++j)
                p[j] = __builtin_amdgcn_exp2f(sv[8 * wd + j]);
            f32x2 s01 = {p[0], p[1]}, s23 = {p[2], p[3]};
            f32x2 s45 = {p[4], p[5]}, s67 = {p[6], p[7]};
            lp[gi] += (s01 + s23) + (s45 + s67);
            unsigned a0 = pk2bf(p[0], p[1]);
            unsigned a1 = pk2bf(p[2], p[3]);
            unsigned b0 = pk2bf(p[4], p[5]);
            unsigned b1 = pk2bf(p[6], p[7]);
            union { unsigned u[4]; short8 v; } fr;
#if HAVE_PLSWAP
            i32x2 r0 = __builtin_amdgcn_permlane32_swap((int)a0, (int)b0, false, false);
            i32x2 r1 = __builtin_amdgcn_permlane32_swap((int)a1, (int)b1, false, false);
            fr.u[0] = (unsigned)r0.x;
            fr.u[1] = (unsigned)r1.x;
            fr.u[2] = (unsigned)r0.y;
            fr.u[3] = (unsigned)r1.y;
#else
            unsigned r0 = (unsigned)__shfl_xor((int)(hl ? a0 : b0), 32, 64);
            unsigned r1 = (unsigned)__shfl_xor((int)(hl ? a1 : b1), 32, 64);
            fr.u[0] = hl ? r0 : a0;
            fr.u[1] = hl ? r1 : a1;
            fr.u[2] = hl ? b0 : r0;
            fr.u[3] = hl ? b1 : r1;
#endif
            dst[wd] = fr.v;
        }
    };

    // PV from Vbuf base vb: 4 V-frag reads, each feeding BOTH P groups (2x reuse)
    auto pv = [&](int vb) {
        #pragma unroll
        for (int sp = 0; sp < 2; ++sp) {
            short8 v0 = *(const short8*)(L + vb + voff[sp]);
            short8 v1 = *(const short8*)(L + vb + 4096 + voff[sp]);
            oc[0] = MFMA32(pfA[sp], v0, oc[0]);
            oc[1] = MFMA32(pfA[sp], v1, oc[1]);
            oc[2] = MFMA32(pfB[sp], v0, oc[2]);
            oc[3] = MFMA32(pfB[sp], v1, oc[3]);
        }
    };

    // ---- prologue: K0,V0,K1 in flight; pf = P(0) ----
    issueK(KB0, 0); issueV(VB0, 0); issueK(KB1, 1);
    __syncthreads();
    qk(KB0);
    softmax_pack(snA, pfA, 0);
    softmax_pack(snB, pfB, 1);

    // ---- pipelined main loop, manually unrolled x2, literal bases (r4 structure) ----
    #pragma unroll 1
    for (int t = 0; t < NITER - 2; t += 2) {
        __syncthreads();                 // K(t+1)@KB1, V(t)@VB0 ready
        issueK(KB0, t + 2);
        issueV(VB1, t + 1);
        qk(KB1);
        pv(VB0);
        softmax_pack(snA, pfA, 0);
        softmax_pack(snB, pfB, 1);
        __syncthreads();                 // K(t+2)@KB0, V(t+1)@VB1 ready
        issueK(KB1, t + 3);
        issueV(VB0, t + 2);
        qk(KB0);
        pv(VB1);
        softmax_pack(snA, pfA, 0);
        softmax_pack(snB, pfB, 1);
    }

    // ---- epilogue tiles NITER-2, NITER-1 ----
    __syncthreads();
    issueV(VB1, NITER - 1);
    qk(KB1);
    pv(VB0);
    softmax_pack(snA, pfA, 0);
    softmax_pack(snB, pfB, 1);
    __syncthreads();                     // V(NITER-1)@VB1 ready
    pv(VB1);

    // ---- cross-wk combine: l then O, via LDS (waves (wq,0)+(wq,1) pair up) ----
    float lA = lp[0].x + lp[0].y;  lA += __shfl_xor(lA, 32, 64);
    float lB = lp[1].x + lp[1].y;  lB += __shfl_xor(lB, 32, 64);

    __syncthreads();                     // all pv reads done; L reusable
    if (lane < 32) {                     // l exchange: [w][grp][q32] floats (1 KB)
        *(float*)(L + ((w * 2 + 0) * 32 + m31) * 4) = lA;
        *(float*)(L + ((w * 2 + 1) * 32 + m31) * 4) = lB;
    }
    __syncthreads();
    {
        const int pw = w ^ 1;            // partner wave (other key half, same wq)
        lA += *(const float*)(L + ((pw * 2 + 0) * 32 + m31) * 4);
        lB += *(const float*)(L + ((pw * 2 + 1) * 32 + m31) * 4);
    }
    const float linvA = 1.0f / lA;
    const float linvB = 1.0f / lB;

    __syncthreads();                     // l reads done before O overwrite
    if (wk == 1) {                       // wk=1 publishes O partials (16 KB per wq)
        #pragma unroll
        for (int i = 0; i < 4; ++i)
            *(f32x16*)(L + wq * 16384 + i * 4096 + lane * 64) = oc[i];
    }
    __syncthreads();
    if (wk == 0) {                       // wk=0 combines, scales, stores
        f32x16 pr[4];
        #pragma unroll
        for (int i = 0; i < 4; ++i)
            pr[i] = *(const f32x16*)(L + wq * 16384 + i * 4096 + lane * 64);
        #pragma unroll
        for (int grp = 0; grp < 2; ++grp) {
            #pragma unroll
            for (int dt = 0; dt < 2; ++dt) {
                #pragma unroll
                for (int reg = 0; reg < 16; ++reg) {
                    const int qp = (reg & 3) + 8 * (reg >> 2) + 4 * hl;
                    const float rl = __shfl(grp ? linvB : linvA, qp, 64);
                    const int q = q0 + wq * 64 + grp * 32 + qp;
                    const float val = oc[grp * 2 + dt][reg] + pr[grp * 2 + dt][reg];
                    Ob[(size_t)q * DH + 32 * dt + m31] = val * rl;
                }
            }
        }
    }
}

extern "C" void kernel_launch(void* const* d_in, const int* in_sizes, int n_in,
                              void* d_out, int out_size, void* d_ws, size_t ws_size,
                              hipStream_t stream) {
    const float* Q = (const float*)d_in[0];
    const float* K = (const float*)d_in[1];
    const float* V = (const float*)d_in[2];
    float* O = (float*)d_out;

    // workspace: bf16 K (12.6 MB) + bf16 V^T (12.6 MB)
    short* Kb  = (short*)d_ws;
    short* Vtg = Kb + (size_t)NBH * SQ * DH;

    prepass<<<dim3(KCONV_BLOCKS + NBH * 32), dim3(256), 0, stream>>>(K, Kb, V, Vtg);
    // 768 blocks, XCD-swizzled (head-locality in per-XCD L2); 32 KB LDS, 3 blocks/CU
    attn_fused_kernel<<<dim3(NBH * NQT), dim3(256), 0, stream>>>(Q, Kb, Vtg, O);
}

// Round 10
// 170.913 us; speedup vs baseline: 1.1495x; 1.1495x over previous
//
#include <hip/hip_runtime.h>

#define SQ 2048
#define DH 64
#define NH 12
#define NBH 48          // B*H
#define QTILE 128       // q rows per block (32 per wave)
#define KTILE 64        // keys per iteration
#define NITER (SQ / KTILE)
#define NQT (SQ / QTILE)   // 16 q-tiles -> 768 blocks = 3 blocks/CU

// LDS arena bases (literal)
#define KB0 0
#define KB1 8192
#define VB0 16384
#define VB1 24576

typedef short short8 __attribute__((ext_vector_type(8)));
typedef float f32x2  __attribute__((ext_vector_type(2)));
typedef float f32x4  __attribute__((ext_vector_type(4)));
typedef float f32x16 __attribute__((ext_vector_type(16)));
typedef int   i32x2 __attribute__((ext_vector_type(2)));
typedef int   i32x4 __attribute__((ext_vector_type(4)));

#define MFMA32(a, b, c) __builtin_amdgcn_mfma_f32_32x32x16_bf16(a, b, c, 0, 0, 0)

typedef __attribute__((address_space(1))) const void* gas_ptr;
typedef __attribute__((address_space(3))) void* las_ptr;

__device__ __forceinline__ void load_lds16(const void* g, void* l) {
    // 16B/lane direct global->LDS DMA; LDS dest = wave-uniform base + lane*16
    __builtin_amdgcn_global_load_lds((gas_ptr)g, (las_ptr)l, 16, 0, 0);
}

// two fp32 -> packed bf16x2 (low = a, high = b), RTNE
#if defined(__has_builtin) && __has_builtin(__builtin_amdgcn_cvt_pk_bf16_f32)
typedef __bf16 bf16x2_t __attribute__((ext_vector_type(2)));
__device__ __forceinline__ unsigned pk2bf(float a, float b) {
    bf16x2_t v = __builtin_amdgcn_cvt_pk_bf16_f32(a, b);
    union { bf16x2_t v; unsigned u; } c; c.v = v; return c.u;
}
#else
__device__ __forceinline__ unsigned pk2bf(float a, float b) {
    union { float f; unsigned u; } x, y; x.f = a; y.f = b;
    unsigned ra = x.u + 0x7FFFu + ((x.u >> 16) & 1u);
    unsigned rb = y.u + 0x7FFFu + ((y.u >> 16) & 1u);
    return (ra >> 16) | (rb & 0xFFFF0000u);
}
#endif

#ifdef __has_builtin
#if __has_builtin(__builtin_amdgcn_permlane32_swap)
#define HAVE_PLSWAP 1
#else
#define HAVE_PLSWAP 0
#endif
#else
#define HAVE_PLSWAP 0
#endif

// ------- fused pre-pass: K fp32->bf16 (blocks 0..3071)  |  V transpose (rest) -------
#define KCONV_BLOCKS (NBH * SQ * DH / 8 / 256)   // 3072
__global__ __launch_bounds__(256)
void prepass(const float* __restrict__ K, short* __restrict__ Kb,
             const float* __restrict__ V, short* __restrict__ Vt) {
    __shared__ float Ls[64][68];   // transpose staging (+4 pad)
    if (blockIdx.x < KCONV_BLOCKS) {
        const size_t i = (size_t)(blockIdx.x * 256 + threadIdx.x) * 8;
        f32x4 a = *(const f32x4*)&K[i];
        f32x4 b = *(const f32x4*)&K[i + 4];
        unsigned o[4] = { pk2bf(a[0], a[1]), pk2bf(a[2], a[3]),
                          pk2bf(b[0], b[1]), pk2bf(b[2], b[3]) };
        *(i32x4*)&Kb[i] = *(i32x4*)o;
        return;
    }
    const int bx = blockIdx.x - KCONV_BLOCKS;
    const int st = bx & 31;       // s tile
    const int bh = bx >> 5;
    const int b = bh / NH, h = bh % NH;
    const int s0 = st * 64;
    const float* src = V + ((size_t)b * SQ * NH + (size_t)h) * DH;
    const int dg = threadIdx.x & 15;   // d = 4*dg
    const int sl = threadIdx.x >> 4;   // 0..15
    #pragma unroll
    for (int p = 0; p < 4; ++p) {
        const int row = p * 16 + sl;
        *(f32x4*)&Ls[row][dg * 4] =
            *(const f32x4*)&src[(size_t)(s0 + row) * (NH * DH) + dg * 4];
    }
    __syncthreads();
    const int dr = threadIdx.x >> 2;        // d row 0..63
    const int sc = (threadIdx.x & 3) * 16;  // s chunk
    unsigned out[8];
    #pragma unroll
    for (int jj = 0; jj < 8; ++jj)
        out[jj] = pk2bf(Ls[sc + 2 * jj][dr], Ls[sc + 2 * jj + 1][dr]);
    short* dst = Vt + (size_t)bh * DH * SQ + (size_t)dr * SQ + s0 + sc;
    *(i32x4*)(dst)     = *(i32x4*)&out[0];
    *(i32x4*)(dst + 8) = *(i32x4*)&out[4];
}

// ---------------- main fused attention (32x32x16 MFMA, P-carry pipeline) ----------------
// Iter t: {sync; DMA K(t+2),V(t+1); QK(t+1)->sn [MFMA]; PV(t) from pfc [independent MFMA,
// issues under sn's latency]; pfc = softmax(sn) [VALU]}.
// This is the best harness-verified configuration (r4: 78.8-80.8us attn, VGPR 64, zero
// scratch). Variants A/B'd and rejected: pv-first reorder (corrupts under 2x-reuse
// pressure, r8), counted-vmcnt 3-ring (neutral, r6), setprio+lb4 bundle (worse, r5),
// 2x-reuse decompositions (spill r7 / unexplained fails r8-r9).
__global__ __launch_bounds__(256, 3)
void attn_fused_kernel(const float* __restrict__ Q,
                       const short* __restrict__ Kb,   // bf16 [BH][S][D]
                       const short* __restrict__ Vtg,  // bf16 [BH][D][S]
                       float* __restrict__ O) {
    // Kbuf j at KB(j&1) (halves +0 rows0-31, +4096 rows32-63)
    // Vbuf j at VB(j&1) (halves +0 d0-31,    +4096 d32-63)
    // XOR chunk swizzle (chunk c of row r at c^(r&7)); unpadded 128B rows.
    __shared__ __align__(16) char L[32768];

    const int tid  = threadIdx.x;
    const int lane = tid & 63;
    const int w    = tid >> 6;
    const int m31  = lane & 31;     // MFMA row/col index
    const int hl   = lane >> 5;     // half-wave 0/1
    const int l7   = lane & 7;

    // ---- XCD-locality swizzle: dispatch round-robins XCDs by (bx & 7).
    const int bx  = blockIdx.x;
    const int xcd = bx & 7;
    const int i96 = bx >> 3;          // 0..95
    const int bh  = xcd * 6 + (i96 % 6);
    const int qt  = i96 / 6;          // 0..15
    const int q0 = qt * QTILE;

    const float* Qb  = Q   + (size_t)bh * SQ * DH;
    const short* Kbh = Kb  + (size_t)bh * SQ * DH;
    const short* Vbh = Vtg + (size_t)bh * DH * SQ;
    float*       Ob  = O   + (size_t)bh * SQ * DH;

    // scale folded into Q, exp as exp2: 1/sqrt(768) * log2(e)
    const float qscale = 0.03608439182435161f * 1.4426950408889634f;

    // ---- Q fragments (B operand: n=m31 -> q row, k=16*s+8*hl+j) ----
    short8 qf[4];
    {
        const int qrow = q0 + 32 * w + m31;
        #pragma unroll
        for (int s = 0; s < 4; ++s) {
            const float* src = Qb + (size_t)qrow * DH + 16 * s + 8 * hl;
            f32x4 qa = *(const f32x4*)src;
            f32x4 qb = *(const f32x4*)(src + 4);
            union { unsigned u[4]; short8 v; } f;
            f.u[0] = pk2bf(qa[0] * qscale, qa[1] * qscale);
            f.u[1] = pk2bf(qa[2] * qscale, qa[3] * qscale);
            f.u[2] = pk2bf(qb[0] * qscale, qb[1] * qscale);
            f.u[3] = pk2bf(qb[2] * qscale, qb[3] * qscale);
            qf[s] = f.v;
        }
    }

    // ---- staging source pointers (lane-constant swizzle) ----
    const int gk = (lane & 7) ^ (lane >> 3);
    const int rr = w * 8 + (lane >> 3);
    const short* kg0 = Kbh + (size_t)rr * DH + gk * 8;
    const short* kg1 = kg0 + 32 * DH;
    const short* vg0 = Vbh + (size_t)rr * SQ + gk * 8;
    const short* vg1 = vg0 + 32 * SQ;
    const int wslot = w * 1024;   // scalar

    // ---- loop-invariant per-lane LDS frag addresses (bytes) ----
    int aoff[4];
    #pragma unroll
    for (int s = 0; s < 4; ++s) aoff[s] = m31 * 128 + (((2 * s + hl) ^ l7) * 16);

    // ---- pipeline state: all captured named vars / constant-indexed arrays ----
    f32x16 o0 = {}, o1 = {};   // output accumulators
    f32x16 sn0, sn1;           // scores of the tile being softmaxed next
    short8 pfc[4];             // carried packed P fragments
    f32x2 lp2 = {0.f, 0.f};    // row-sum accumulator (packed)

    // issue K tile t into Kbuf base kb (2 KB/wave via DMA)
    auto issueK = [&](int kb, int t) {
        const short* p0 = kg0 + (size_t)t * (KTILE * DH);
        const short* p1 = kg1 + (size_t)t * (KTILE * DH);
        load_lds16(p0, L + kb + wslot);
        load_lds16(p1, L + kb + 4096 + wslot);
    };
    // issue V tile t into Vbuf base vb
    auto issueV = [&](int vb, int t) {
        const short* p0 = vg0 + (size_t)t * KTILE;
        const short* p1 = vg1 + (size_t)t * KTILE;
        load_lds16(p0, L + vb + wslot);
        load_lds16(p1, L + vb + 4096 + wslot);
    };

    // QK^T from Kbuf base kb -> writes captured sn0, sn1
    auto qk = [&](int kb) {
        f32x16 a0 = {}, a1 = {};
        #pragma unroll
        for (int s = 0; s < 4; ++s) {
            short8 ka0 = *(const short8*)(L + kb + aoff[s]);
            short8 ka1 = *(const short8*)(L + kb + 4096 + aoff[s]);
            a0 = MFMA32(ka0, qf[s], a0);
            a1 = MFMA32(ka1, qf[s], a1);
        }
        sn0 = a0; sn1 = a1;
    };

    // exp + in-register C->A relayout; consumes one score half into dst[0..1]
    auto softmax_pack = [&](const f32x16& sv, short8* dst) {
        #pragma unroll
        for (int wd = 0; wd < 2; ++wd) {
            float p[8];
            #pragma unroll
            for (int j = 0; j < 8; ++j)
                p[j] = __builtin_amdgcn_exp2f(sv[8 * wd + j]);
            // row-sum via packed v_pk_add_f32
            f32x2 s01 = {p[0], p[1]}, s23 = {p[2], p[3]};
            f32x2 s45 = {p[4], p[5]}, s67 = {p[6], p[7]};
            lp2 += (s01 + s23) + (s45 + s67);
            unsigned a0 = pk2bf(p[0], p[1]);   // kk 4hl+{0,1}
            unsigned a1 = pk2bf(p[2], p[3]);   // kk 4hl+{2,3}
            unsigned b0 = pk2bf(p[4], p[5]);   // kk 8+4hl+{0,1}
            unsigned b1 = pk2bf(p[6], p[7]);   // kk 8+4hl+{2,3}
            union { unsigned u[4]; short8 v; } fr;
#if HAVE_PLSWAP
            // r.x = {lo: a[0:31]  | hi: b[0:31]}  = A-frag word0
            // r.y = {lo: a[32:63] | hi: b[32:63]} = A-frag word2
            i32x2 r0 = __builtin_amdgcn_permlane32_swap((int)a0, (int)b0, false, false);
            i32x2 r1 = __builtin_amdgcn_permlane32_swap((int)a1, (int)b1, false, false);
            fr.u[0] = (unsigned)r0.x;
            fr.u[1] = (unsigned)r1.x;
            fr.u[2] = (unsigned)r0.y;
            fr.u[3] = (unsigned)r1.y;
#else
            unsigned r0 = (unsigned)__shfl_xor((int)(hl ? a0 : b0), 32, 64);
            unsigned r1 = (unsigned)__shfl_xor((int)(hl ? a1 : b1), 32, 64);
            fr.u[0] = hl ? r0 : a0;
            fr.u[1] = hl ? r1 : a1;
            fr.u[2] = hl ? b0 : r0;
            fr.u[3] = hl ? b1 : r1;
#endif
            dst[wd] = fr.v;
        }
    };
    // softmax both score halves -> pfc[0..3]
    auto softmax2 = [&]() {
        softmax_pack(sn0, &pfc[0]);
        softmax_pack(sn1, &pfc[2]);
    };

    // PV accumulate from Vbuf base vb with carried pfc
    auto pv = [&](int vb) {
        #pragma unroll
        for (int s = 0; s < 4; ++s) {
            short8 vv0 = *(const short8*)(L + vb + aoff[s]);
            short8 vv1 = *(const short8*)(L + vb + 4096 + aoff[s]);
            o0 = MFMA32(pfc[s], vv0, o0);
            o1 = MFMA32(pfc[s], vv1, o1);
        }
    };

    // ---- prologue: K0,V0,K1 in flight; pfc = P(0) ----
    issueK(KB0, 0); issueV(VB0, 0); issueK(KB1, 1);
    __syncthreads();
    qk(KB0);
    softmax2();

    // ---- pipelined main loop, manually unrolled x2 (tiles t..t+1), literal bases ----
    // Barrier at top of each half: all waves finished the previous half's QK/PV, so the
    // buffer being overwritten is dead; drains the two DMAs issued one half earlier.
    #pragma unroll 1
    for (int t = 0; t < NITER - 2; t += 2) {
        // tile t: QK(t+1) from KB1, PV(t) from VB0
        __syncthreads();                 // K(t+1)@KB1, V(t)@VB0 ready
        issueK(KB0, t + 2);
        issueV(VB1, t + 1);
        qk(KB1);
        pv(VB0);
        softmax2();                      // pfc = P(t+1)
        // tile t+1: QK(t+2) from KB0, PV(t+1) from VB1
        __syncthreads();                 // K(t+2)@KB0, V(t+1)@VB1 ready
        issueK(KB1, t + 3);              // t<=NITER-4 -> t+3 <= NITER-1, always valid
        issueV(VB0, t + 2);
        qk(KB0);
        pv(VB1);
        softmax2();                      // pfc = P(t+2)
    }

    // ---- epilogue: tiles NITER-2, NITER-1 (K(NITER-1)@KB1, V(NITER-2)@VB0 in flight) ----
    __syncthreads();
    issueV(VB1, NITER - 1);
    qk(KB1);                             // S(NITER-1)
    pv(VB0);                             // PV(NITER-2)
    softmax2();                          // pfc = P(NITER-1)
    __syncthreads();                     // V(NITER-1)@VB1 ready
    pv(VB1);                             // PV(NITER-1)

    // ---- finalize: l(q=m31) = lp(lane) + lp(lane^32); invert; scatter ----
    float lp = lp2.x + lp2.y;
    float v = lp;
    v += __shfl_xor(v, 32, 64);
    const float linv = 1.0f / v;

    #pragma unroll
    for (int dt = 0; dt < 2; ++dt) {
        const f32x16& o = dt ? o1 : o0;
        #pragma unroll
        for (int reg = 0; reg < 16; ++reg) {
            const int qp = (reg & 3) + 8 * (reg >> 2) + 4 * hl;
            const float rl = __shfl(linv, qp, 64);
            const int q = q0 + 32 * w + qp;
            Ob[(size_t)q * DH + 32 * dt + m31] = o[reg] * rl;
        }
    }
}

extern "C" void kernel_launch(void* const* d_in, const int* in_sizes, int n_in,
                              void* d_out, int out_size, void* d_ws, size_t ws_size,
                              hipStream_t stream) {
    const float* Q = (const float*)d_in[0];
    const float* K = (const float*)d_in[1];
    const float* V = (const float*)d_in[2];
    float* O = (float*)d_out;

    // workspace: bf16 K (12.6 MB) + bf16 V^T (12.6 MB)
    short* Kb  = (short*)d_ws;
    short* Vtg = Kb + (size_t)NBH * SQ * DH;

    prepass<<<dim3(KCONV_BLOCKS + NBH * 32), dim3(256), 0, stream>>>(K, Kb, V, Vtg);
    // 768 blocks, XCD-swizzled (head-locality in per-XCD L2); 32 KB LDS, 3 blocks/CU
    attn_fused_kernel<<<dim3(NBH * NQT), dim3(256), 0, stream>>>(Q, Kb, Vtg, O);
}